// Round 2
// baseline (320.002 us; speedup 1.0000x reference)
//
#include <hip/hip_runtime.h>
#include <cmath>

#define HH 512
#define WW 512
#define TW 32
#define TH 64
#define HALO 5
#define INW 42   /* TW + 10 */
#define INH 74   /* TH + 10 */
#define SPS 44   /* sp/st row stride (dwords), mult of 4 */
#define HPS 36   /* hp row stride (dwords), mult of 4 */
#define C1F 0.0001f
#define C2F 0.0009f

struct GaussW { float w[11]; };

__global__ __launch_bounds__(256, 2) void ssim_tile_kernel(
    const float* __restrict__ pred, const float* __restrict__ targ,
    float* __restrict__ partial, GaussW gw)
{
    __shared__ __align__(16) float sp[INH][SPS];
    __shared__ __align__(16) float st[INH][SPS];
    __shared__ __align__(16) float hp[5][INH][HPS];
    __shared__ float wred[4];

    const int tid = threadIdx.x;
    const int bx = blockIdx.x, by = blockIdx.y, bz = blockIdx.z;
    const int gx0 = bx * TW - HALO;
    const int gy0 = by * TH - HALO;
    const size_t plane = (size_t)bz * (size_t)(HH * WW);

    // ---- Phase A: stage global -> LDS (zero-padded halo) ----
    for (int i = tid; i < INH * INW; i += 256) {
        int r = i / INW;
        int c = i - r * INW;
        int gr = gy0 + r, gc = gx0 + c;
        float p = 0.f, t = 0.f;
        if ((unsigned)gr < (unsigned)HH && (unsigned)gc < (unsigned)WW) {
            size_t idx = plane + (size_t)gr * WW + gc;
            p = pred[idx];
            t = targ[idx];
        }
        sp[r][c] = p;
        st[r][c] = t;
    }
    __syncthreads();

    // ---- Phase B: horizontal Gaussian, 4 output cols per task, b128 I/O ----
    // tasks: 74 rows x 8 col-groups = 592
    for (int i = tid; i < INH * 8; i += 256) {
        int r  = i >> 3;
        int c0 = (i & 7) << 2;

        float pin[16], tin[16];
        *(float4*)&pin[0]  = *(const float4*)&sp[r][c0];
        *(float4*)&pin[4]  = *(const float4*)&sp[r][c0 + 4];
        *(float4*)&pin[8]  = *(const float4*)&sp[r][c0 + 8];
        *(float4*)&pin[12] = *(const float4*)&sp[r][c0 + 12];
        *(float4*)&tin[0]  = *(const float4*)&st[r][c0];
        *(float4*)&tin[4]  = *(const float4*)&st[r][c0 + 4];
        *(float4*)&tin[8]  = *(const float4*)&st[r][c0 + 8];
        *(float4*)&tin[12] = *(const float4*)&st[r][c0 + 12];

        float pp[14], tt[14], pt[14];
        #pragma unroll
        for (int k = 0; k < 14; k++) {
            pp[k] = pin[k] * pin[k];
            tt[k] = tin[k] * tin[k];
            pt[k] = pin[k] * tin[k];
        }

        float s1[4]  = {0,0,0,0}, s2[4]  = {0,0,0,0};
        float s11[4] = {0,0,0,0}, s22[4] = {0,0,0,0}, s12[4] = {0,0,0,0};
        #pragma unroll
        for (int k = 0; k < 11; k++) {
            float wk = gw.w[k];
            #pragma unroll
            for (int j = 0; j < 4; j++) {
                s1[j]  += wk * pin[j + k];
                s2[j]  += wk * tin[j + k];
                s11[j] += wk * pp[j + k];
                s22[j] += wk * tt[j + k];
                s12[j] += wk * pt[j + k];
            }
        }
        *(float4*)&hp[0][r][c0] = make_float4(s1[0],  s1[1],  s1[2],  s1[3]);
        *(float4*)&hp[1][r][c0] = make_float4(s2[0],  s2[1],  s2[2],  s2[3]);
        *(float4*)&hp[2][r][c0] = make_float4(s11[0], s11[1], s11[2], s11[3]);
        *(float4*)&hp[3][r][c0] = make_float4(s22[0], s22[1], s22[2], s22[3]);
        *(float4*)&hp[4][r][c0] = make_float4(s12[0], s12[1], s12[2], s12[3]);
    }
    __syncthreads();

    // ---- Phase C: vertical Gaussian with 4-row register sliding + SSIM ----
    // 128 active lanes: 8 col-groups x 16 row-strips, each 4 cols x 4 rows
    float local = 0.f;
    if (tid < 128) {
        int c0 = (tid & 7) << 2;
        int r0 = (tid >> 3) << 2;   // 0..60

        float acc[5][4][4];
        #pragma unroll
        for (int f = 0; f < 5; f++)
            #pragma unroll
            for (int rr = 0; rr < 4; rr++)
                #pragma unroll
                for (int cc = 0; cc < 4; cc++)
                    acc[f][rr][cc] = 0.f;

        #pragma unroll
        for (int j = 0; j < 14; j++) {
            float v[5][4];
            #pragma unroll
            for (int f = 0; f < 5; f++)
                *(float4*)&v[f][0] = *(const float4*)&hp[f][r0 + j][c0];
            #pragma unroll
            for (int rr = 0; rr < 4; rr++) {
                int k = j - rr;
                if (k >= 0 && k < 11) {
                    float wk = gw.w[k];
                    #pragma unroll
                    for (int f = 0; f < 5; f++)
                        #pragma unroll
                        for (int cc = 0; cc < 4; cc++)
                            acc[f][rr][cc] += wk * v[f][cc];
                }
            }
        }

        #pragma unroll
        for (int rr = 0; rr < 4; rr++) {
            #pragma unroll
            for (int cc = 0; cc < 4; cc++) {
                float m1  = acc[0][rr][cc], m2  = acc[1][rr][cc];
                float e11 = acc[2][rr][cc], e22 = acc[3][rr][cc], e12 = acc[4][rr][cc];
                float m1s = m1 * m1, m2s = m2 * m2, m12 = m1 * m2;
                float num = (2.f * m12 + C1F) * (2.f * (e12 - m12) + C2F);
                float den = (m1s + m2s + C1F) * ((e11 - m1s) + (e22 - m2s) + C2F);
                local += num / den;
            }
        }
    }

    // ---- block reduction ----
    #pragma unroll
    for (int off = 32; off > 0; off >>= 1)
        local += __shfl_down(local, off, 64);
    int lane = tid & 63, wid = tid >> 6;
    if (lane == 0) wred[wid] = local;
    __syncthreads();
    if (tid == 0) {
        int bid = (bz * gridDim.y + by) * gridDim.x + bx;
        partial[bid] = wred[0] + wred[1] + wred[2] + wred[3];
    }
}

__global__ __launch_bounds__(1024) void ssim_finalize_kernel(
    const float* __restrict__ partial, int n, float inv_count,
    float* __restrict__ out)
{
    __shared__ float sm[16];
    float s = 0.f;
    for (int i = threadIdx.x; i < n; i += 1024)
        s += partial[i];
    #pragma unroll
    for (int off = 32; off > 0; off >>= 1)
        s += __shfl_down(s, off, 64);
    int lane = threadIdx.x & 63, wid = threadIdx.x >> 6;
    if (lane == 0) sm[wid] = s;
    __syncthreads();
    if (threadIdx.x == 0) {
        float tot = 0.f;
        #pragma unroll
        for (int i = 0; i < 16; i++) tot += sm[i];
        out[0] = 1.0f - tot * inv_count;
    }
}

extern "C" void kernel_launch(void* const* d_in, const int* in_sizes, int n_in,
                              void* d_out, int out_size, void* d_ws, size_t ws_size,
                              hipStream_t stream)
{
    const float* pred = (const float*)d_in[0];
    const float* targ = (const float*)d_in[1];
    float* out = (float*)d_out;
    float* partial = (float*)d_ws;

    const int total = in_sizes[0];                 // 16*3*512*512 = 12582912
    const int nplanes = total / (HH * WW);         // 48

    GaussW gw;
    double g[11], s = 0.0;
    for (int i = 0; i < 11; i++) {
        double d = (double)(i - 5);
        g[i] = exp(-d * d / 4.5);
        s += g[i];
    }
    for (int i = 0; i < 11; i++) gw.w[i] = (float)(g[i] / s);

    dim3 grid(WW / TW, HH / TH, nplanes);          // 16 x 8 x 48 = 6144 blocks
    ssim_tile_kernel<<<grid, 256, 0, stream>>>(pred, targ, partial, gw);

    const int nblocks = (WW / TW) * (HH / TH) * nplanes;
    const float inv_count = 1.0f / (float)total;
    ssim_finalize_kernel<<<1, 1024, 0, stream>>>(partial, nblocks, inv_count, out);
}

// Round 3
// 191.838 us; speedup vs baseline: 1.6681x; 1.6681x over previous
//
#include <hip/hip_runtime.h>
#include <cmath>

#define HH 512
#define WW 512
#define TW 32
#define TH 64
#define INH 74          /* TH + 10 halo rows */
#define HPS 36          /* hp row stride in dwords (mult of 4) */
#define C1F 0.0001f
#define C2F 0.0009f

struct GaussW { float w[11]; };

__device__ __forceinline__ void hconv_store(
    const float p[14], const float t[14],
    float (*hp)[INH][HPS], int r, int c0, const GaussW& gw)
{
    float s1[4]  = {0,0,0,0}, s2[4]  = {0,0,0,0};
    float s11[4] = {0,0,0,0}, s22[4] = {0,0,0,0}, s12[4] = {0,0,0,0};
    #pragma unroll
    for (int k = 0; k < 11; k++) {
        float wk = gw.w[k];
        #pragma unroll
        for (int o = 0; o < 4; o++) {
            float pv = p[o + k], tv = t[o + k];
            float wp = wk * pv, wt = wk * tv;
            s1[o]  += wp;
            s2[o]  += wt;
            s11[o] += wp * pv;
            s22[o] += wt * tv;
            s12[o] += wp * tv;
        }
    }
    *(float4*)&hp[0][r][c0] = make_float4(s1[0],  s1[1],  s1[2],  s1[3]);
    *(float4*)&hp[1][r][c0] = make_float4(s2[0],  s2[1],  s2[2],  s2[3]);
    *(float4*)&hp[2][r][c0] = make_float4(s11[0], s11[1], s11[2], s11[3]);
    *(float4*)&hp[3][r][c0] = make_float4(s22[0], s22[1], s22[2], s22[3]);
    *(float4*)&hp[4][r][c0] = make_float4(s12[0], s12[1], s12[2], s12[3]);
}

__global__ __launch_bounds__(256) void ssim_tile_kernel(
    const float* __restrict__ pred, const float* __restrict__ targ,
    float* __restrict__ partial, GaussW gw)
{
    __shared__ __align__(16) float hp[5][INH][HPS];
    __shared__ float wred[4];

    const int tid = threadIdx.x;
    const int bx = blockIdx.x, by = blockIdx.y, bz = blockIdx.z;
    const int gx0 = bx * TW;
    const int gy0 = by * TH - 5;
    const size_t plane = (size_t)bz * (size_t)(HH * WW);

    const bool interior =
        (bx > 0) && (bx < (WW / TW) - 1) && (by > 0) && (by < (HH / TH) - 1);

    // ---- Phase B: horizontal Gaussian directly from global memory ----
    // tasks: 74 rows x 8 col-groups = 592; each computes 4 output cols
    if (interior) {
        for (int i = tid; i < INH * (TW / 4); i += 256) {
            int r = i >> 3;
            int j = i & 7;
            int gr = gy0 + r;
            const float* prow = pred + plane + (size_t)gr * WW + (gx0 + 4 * j - 5);
            const float* trow = targ + plane + (size_t)gr * WW + (gx0 + 4 * j - 5);
            float p[14], t[14];
            #pragma unroll
            for (int m = 0; m < 14; m++) { p[m] = prow[m]; t[m] = trow[m]; }
            hconv_store(p, t, hp, r, 4 * j, gw);
        }
    } else {
        for (int i = tid; i < INH * (TW / 4); i += 256) {
            int r = i >> 3;
            int j = i & 7;
            int gr = gy0 + r;
            float p[14], t[14];
            if ((unsigned)gr < (unsigned)HH) {
                const size_t rb = plane + (size_t)gr * WW;
                int cbase = gx0 + 4 * j - 5;
                #pragma unroll
                for (int m = 0; m < 14; m++) {
                    int gc = cbase + m;
                    int cc = min(max(gc, 0), WW - 1);
                    bool in = (unsigned)gc < (unsigned)WW;
                    float pv = pred[rb + cc];
                    float tv = targ[rb + cc];
                    p[m] = in ? pv : 0.f;
                    t[m] = in ? tv : 0.f;
                }
            } else {
                #pragma unroll
                for (int m = 0; m < 14; m++) { p[m] = 0.f; t[m] = 0.f; }
            }
            hconv_store(p, t, hp, r, 4 * j, gw);
        }
    }
    __syncthreads();

    // ---- Phase C: vertical Gaussian, 4 rows x 2 cols per lane + SSIM ----
    float local = 0.f;
    {
        int c0 = (tid & 15) << 1;   // 0..30
        int r0 = (tid >> 4) << 2;   // 0..60

        float acc[5][4][2];
        #pragma unroll
        for (int f = 0; f < 5; f++)
            #pragma unroll
            for (int rr = 0; rr < 4; rr++) {
                acc[f][rr][0] = 0.f;
                acc[f][rr][1] = 0.f;
            }

        #pragma unroll
        for (int jj = 0; jj < 14; jj++) {
            float v[5][2];
            #pragma unroll
            for (int f = 0; f < 5; f++)
                *(float2*)&v[f][0] = *(const float2*)&hp[f][r0 + jj][c0];
            #pragma unroll
            for (int rr = 0; rr < 4; rr++) {
                int k = jj - rr;
                if (k >= 0 && k < 11) {
                    float wk = gw.w[k];
                    #pragma unroll
                    for (int f = 0; f < 5; f++) {
                        acc[f][rr][0] += wk * v[f][0];
                        acc[f][rr][1] += wk * v[f][1];
                    }
                }
            }
        }

        #pragma unroll
        for (int rr = 0; rr < 4; rr++) {
            #pragma unroll
            for (int cc = 0; cc < 2; cc++) {
                float m1  = acc[0][rr][cc], m2  = acc[1][rr][cc];
                float e11 = acc[2][rr][cc], e22 = acc[3][rr][cc], e12 = acc[4][rr][cc];
                float m1s = m1 * m1, m2s = m2 * m2, m12 = m1 * m2;
                float num = (2.f * m12 + C1F) * (2.f * (e12 - m12) + C2F);
                float den = (m1s + m2s + C1F) * ((e11 - m1s) + (e22 - m2s) + C2F);
                local += num / den;
            }
        }
    }

    // ---- block reduction ----
    #pragma unroll
    for (int off = 32; off > 0; off >>= 1)
        local += __shfl_down(local, off, 64);
    int lane = tid & 63, wid = tid >> 6;
    if (lane == 0) wred[wid] = local;
    __syncthreads();
    if (tid == 0) {
        int bid = (bz * gridDim.y + by) * gridDim.x + bx;
        partial[bid] = wred[0] + wred[1] + wred[2] + wred[3];
    }
}

__global__ __launch_bounds__(256) void ssim_finalize_kernel(
    const float* __restrict__ partial, int n, float inv_count,
    float* __restrict__ out)
{
    __shared__ float sm[4];
    float s = 0.f;
    for (int i = threadIdx.x; i < n; i += 256)
        s += partial[i];
    #pragma unroll
    for (int off = 32; off > 0; off >>= 1)
        s += __shfl_down(s, off, 64);
    int lane = threadIdx.x & 63, wid = threadIdx.x >> 6;
    if (lane == 0) sm[wid] = s;
    __syncthreads();
    if (threadIdx.x == 0)
        out[0] = 1.0f - (sm[0] + sm[1] + sm[2] + sm[3]) * inv_count;
}

extern "C" void kernel_launch(void* const* d_in, const int* in_sizes, int n_in,
                              void* d_out, int out_size, void* d_ws, size_t ws_size,
                              hipStream_t stream)
{
    const float* pred = (const float*)d_in[0];
    const float* targ = (const float*)d_in[1];
    float* out = (float*)d_out;
    float* partial = (float*)d_ws;

    const int total = in_sizes[0];                 // 16*3*512*512 = 12582912
    const int nplanes = total / (HH * WW);         // 48

    GaussW gw;
    double g[11], s = 0.0;
    for (int i = 0; i < 11; i++) {
        double d = (double)(i - 5);
        g[i] = exp(-d * d / 4.5);
        s += g[i];
    }
    for (int i = 0; i < 11; i++) gw.w[i] = (float)(g[i] / s);

    dim3 grid(WW / TW, HH / TH, nplanes);          // 16 x 8 x 48 = 6144 blocks
    ssim_tile_kernel<<<grid, 256, 0, stream>>>(pred, targ, partial, gw);

    const int nblocks = (WW / TW) * (HH / TH) * nplanes;
    const float inv_count = 1.0f / (float)total;
    ssim_finalize_kernel<<<1, 256, 0, stream>>>(partial, nblocks, inv_count, out);
}

// Round 4
// 190.663 us; speedup vs baseline: 1.6784x; 1.0062x over previous
//
#include <hip/hip_runtime.h>
#include <cmath>

#define HH 512
#define WW 512
#define TW 32
#define TH 64
#define INH 74          /* TH + 10 halo rows */
#define HPS 36          /* hp row stride in dwords (mult of 4) */
#define C1F 0.0001f
#define C2F 0.0009f

struct GaussW { float w[11]; };

__global__ __launch_bounds__(256) void ssim_tile_kernel(
    const float* __restrict__ pred, const float* __restrict__ targ,
    float* __restrict__ partial, GaussW gw)
{
    __shared__ __align__(16) float hp[5][INH][HPS];
    __shared__ float wred[4];

    const int tid = threadIdx.x;
    const int bx = blockIdx.x, by = blockIdx.y, bz = blockIdx.z;
    const int gx0 = bx * TW;
    const int gy0 = by * TH - 5;
    const size_t plane = (size_t)bz * (size_t)(HH * WW);

    const bool xinterior = (bx > 0) && (bx < (WW / TW) - 1);

    // ---- Phase B: horizontal Gaussian directly from global memory ----
    // 592 tasks: 74 rows x 8 col-groups, each computes 4 output cols.
    if (xinterior) {
        for (int i = tid; i < INH * 8; i += 256) {
            int r = i >> 3;
            int c0 = (i & 7) << 2;
            int gr = gy0 + r;
            // p[m]/t[m] hold input col c0-6+m, m=0..15 (need m=1..14)
            float p[16], t[16];
            if ((unsigned)gr < (unsigned)HH) {
                const float* prow = pred + plane + (size_t)gr * WW + (gx0 + c0 - 6);
                const float* trow = targ + plane + (size_t)gr * WW + (gx0 + c0 - 6);
                *(float2*)&p[0]  = *(const float2*)(prow);
                *(float4*)&p[2]  = *(const float4*)(prow + 2);
                *(float4*)&p[6]  = *(const float4*)(prow + 6);
                *(float4*)&p[10] = *(const float4*)(prow + 10);
                *(float2*)&p[14] = *(const float2*)(prow + 14);
                *(float2*)&t[0]  = *(const float2*)(trow);
                *(float4*)&t[2]  = *(const float4*)(trow + 2);
                *(float4*)&t[6]  = *(const float4*)(trow + 6);
                *(float4*)&t[10] = *(const float4*)(trow + 10);
                *(float2*)&t[14] = *(const float2*)(trow + 14);
            } else {
                #pragma unroll
                for (int m = 0; m < 16; m++) { p[m] = 0.f; t[m] = 0.f; }
            }

            float pp[14], tt[14], pt[14];
            #pragma unroll
            for (int m = 0; m < 14; m++) {
                float pv = p[m + 1], tv = t[m + 1];
                pp[m] = pv * pv;
                tt[m] = tv * tv;
                pt[m] = pv * tv;
            }

            float s1[4]  = {0,0,0,0}, s2[4]  = {0,0,0,0};
            float s11[4] = {0,0,0,0}, s22[4] = {0,0,0,0}, s12[4] = {0,0,0,0};
            #pragma unroll
            for (int k = 0; k < 11; k++) {
                float wk = gw.w[k];
                #pragma unroll
                for (int o = 0; o < 4; o++) {
                    s1[o]  += wk * p[o + k + 1];
                    s2[o]  += wk * t[o + k + 1];
                    s11[o] += wk * pp[o + k];
                    s22[o] += wk * tt[o + k];
                    s12[o] += wk * pt[o + k];
                }
            }
            *(float4*)&hp[0][r][c0] = make_float4(s1[0],  s1[1],  s1[2],  s1[3]);
            *(float4*)&hp[1][r][c0] = make_float4(s2[0],  s2[1],  s2[2],  s2[3]);
            *(float4*)&hp[2][r][c0] = make_float4(s11[0], s11[1], s11[2], s11[3]);
            *(float4*)&hp[3][r][c0] = make_float4(s22[0], s22[1], s22[2], s22[3]);
            *(float4*)&hp[4][r][c0] = make_float4(s12[0], s12[1], s12[2], s12[3]);
        }
    } else {
        for (int i = tid; i < INH * 8; i += 256) {
            int r = i >> 3;
            int c0 = (i & 7) << 2;
            int gr = gy0 + r;
            float p[14], t[14];
            if ((unsigned)gr < (unsigned)HH) {
                const size_t rb = plane + (size_t)gr * WW;
                int cbase = gx0 + c0 - 5;
                #pragma unroll
                for (int m = 0; m < 14; m++) {
                    int gc = cbase + m;
                    int cc = min(max(gc, 0), WW - 1);
                    bool in = (unsigned)gc < (unsigned)WW;
                    float pv = pred[rb + cc];
                    float tv = targ[rb + cc];
                    p[m] = in ? pv : 0.f;
                    t[m] = in ? tv : 0.f;
                }
            } else {
                #pragma unroll
                for (int m = 0; m < 14; m++) { p[m] = 0.f; t[m] = 0.f; }
            }

            float s1[4]  = {0,0,0,0}, s2[4]  = {0,0,0,0};
            float s11[4] = {0,0,0,0}, s22[4] = {0,0,0,0}, s12[4] = {0,0,0,0};
            #pragma unroll
            for (int k = 0; k < 11; k++) {
                float wk = gw.w[k];
                #pragma unroll
                for (int o = 0; o < 4; o++) {
                    float pv = p[o + k], tv = t[o + k];
                    float wp = wk * pv, wt = wk * tv;
                    s1[o]  += wp;
                    s2[o]  += wt;
                    s11[o] += wp * pv;
                    s22[o] += wt * tv;
                    s12[o] += wp * tv;
                }
            }
            *(float4*)&hp[0][r][c0] = make_float4(s1[0],  s1[1],  s1[2],  s1[3]);
            *(float4*)&hp[1][r][c0] = make_float4(s2[0],  s2[1],  s2[2],  s2[3]);
            *(float4*)&hp[2][r][c0] = make_float4(s11[0], s11[1], s11[2], s11[3]);
            *(float4*)&hp[3][r][c0] = make_float4(s22[0], s22[1], s22[2], s22[3]);
            *(float4*)&hp[4][r][c0] = make_float4(s12[0], s12[1], s12[2], s12[3]);
        }
    }
    __syncthreads();

    // ---- Phase C: vertical Gaussian, 4 rows x 2 cols per lane + SSIM ----
    float local = 0.f;
    {
        int c0 = (tid & 15) << 1;   // 0..30
        int r0 = (tid >> 4) << 2;   // 0..60

        float acc[5][4][2];
        #pragma unroll
        for (int f = 0; f < 5; f++)
            #pragma unroll
            for (int rr = 0; rr < 4; rr++) {
                acc[f][rr][0] = 0.f;
                acc[f][rr][1] = 0.f;
            }

        #pragma unroll
        for (int jj = 0; jj < 14; jj++) {
            float v[5][2];
            #pragma unroll
            for (int f = 0; f < 5; f++)
                *(float2*)&v[f][0] = *(const float2*)&hp[f][r0 + jj][c0];
            #pragma unroll
            for (int rr = 0; rr < 4; rr++) {
                int k = jj - rr;
                if (k >= 0 && k < 11) {
                    float wk = gw.w[k];
                    #pragma unroll
                    for (int f = 0; f < 5; f++) {
                        acc[f][rr][0] += wk * v[f][0];
                        acc[f][rr][1] += wk * v[f][1];
                    }
                }
            }
        }

        #pragma unroll
        for (int rr = 0; rr < 4; rr++) {
            #pragma unroll
            for (int cc = 0; cc < 2; cc++) {
                float m1  = acc[0][rr][cc], m2  = acc[1][rr][cc];
                float e11 = acc[2][rr][cc], e22 = acc[3][rr][cc], e12 = acc[4][rr][cc];
                float m1s = m1 * m1, m2s = m2 * m2, m12 = m1 * m2;
                float num = (2.f * m12 + C1F) * (2.f * (e12 - m12) + C2F);
                float den = (m1s + m2s + C1F) * ((e11 - m1s) + (e22 - m2s) + C2F);
                local += num * __builtin_amdgcn_rcpf(den);
            }
        }
    }

    // ---- block reduction ----
    #pragma unroll
    for (int off = 32; off > 0; off >>= 1)
        local += __shfl_down(local, off, 64);
    int lane = tid & 63, wid = tid >> 6;
    if (lane == 0) wred[wid] = local;
    __syncthreads();
    if (tid == 0) {
        int bid = (bz * gridDim.y + by) * gridDim.x + bx;
        partial[bid] = wred[0] + wred[1] + wred[2] + wred[3];
    }
}

__global__ __launch_bounds__(256) void ssim_finalize_kernel(
    const float* __restrict__ partial, int n, float inv_count,
    float* __restrict__ out)
{
    __shared__ float sm[4];
    float s = 0.f;
    for (int i = threadIdx.x; i < n; i += 256)
        s += partial[i];
    #pragma unroll
    for (int off = 32; off > 0; off >>= 1)
        s += __shfl_down(s, off, 64);
    int lane = threadIdx.x & 63, wid = threadIdx.x >> 6;
    if (lane == 0) sm[wid] = s;
    __syncthreads();
    if (threadIdx.x == 0)
        out[0] = 1.0f - (sm[0] + sm[1] + sm[2] + sm[3]) * inv_count;
}

extern "C" void kernel_launch(void* const* d_in, const int* in_sizes, int n_in,
                              void* d_out, int out_size, void* d_ws, size_t ws_size,
                              hipStream_t stream)
{
    const float* pred = (const float*)d_in[0];
    const float* targ = (const float*)d_in[1];
    float* out = (float*)d_out;
    float* partial = (float*)d_ws;

    const int total = in_sizes[0];                 // 16*3*512*512 = 12582912
    const int nplanes = total / (HH * WW);         // 48

    GaussW gw;
    double g[11], s = 0.0;
    for (int i = 0; i < 11; i++) {
        double d = (double)(i - 5);
        g[i] = exp(-d * d / 4.5);
        s += g[i];
    }
    for (int i = 0; i < 11; i++) gw.w[i] = (float)(g[i] / s);

    dim3 grid(WW / TW, HH / TH, nplanes);          // 16 x 8 x 48 = 6144 blocks
    ssim_tile_kernel<<<grid, 256, 0, stream>>>(pred, targ, partial, gw);

    const int nblocks = (WW / TW) * (HH / TH) * nplanes;
    const float inv_count = 1.0f / (float)total;
    ssim_finalize_kernel<<<1, 256, 0, stream>>>(partial, nblocks, inv_count, out);
}